// Round 1
// baseline (560.079 us; speedup 1.0000x reference)
//
#include <hip/hip_runtime.h>
#include <hip/hip_bf16.h>
#include <cstddef>

#define EPS 1e-5f
#define NSLOPE 0.01f

typedef __attribute__((ext_vector_type(8))) short s16x8;   // 8 bf16 (4 VGPRs)
typedef __attribute__((ext_vector_type(4))) float f32x4;

union BF8 { unsigned short u[8]; s16x8 v; };

static __device__ inline unsigned short f2bf(float f) {
    unsigned int u = __float_as_uint(f);
    u += 0x7fffu + ((u >> 16) & 1u);   // round-to-nearest-even
    return (unsigned short)(u >> 16);
}

// ---------------- Kernel A: x+=enc@W_enc^T+b_enc; LN1; h=xn@W0^T; s1,s2 ----
__global__ __launch_bounds__(256) void kA(
    const float* __restrict__ x, const float* __restrict__ enc,
    const float* __restrict__ W_enc, const float* __restrict__ b_enc,
    const float* __restrict__ g1, const float* __restrict__ b1,
    const float* __restrict__ W0, const float* __restrict__ Wa,
    float* __restrict__ xnew, unsigned short* __restrict__ hbf,
    float* __restrict__ s1, float* __restrict__ s2)
{
    int t = threadIdx.x;
    int r = t >> 7, c = t & 127;
    long long row = (long long)blockIdx.x * 2 + r;
    __shared__ float encs[2 * 64];
    __shared__ float xns[2 * 128];
    __shared__ float red[4][4];

    if (t < 128) encs[t] = enc[(long long)blockIdx.x * 2 * 64 + t];
    __syncthreads();

    float y = x[row * 128 + c] + b_enc[c];
    const float* we = W_enc + c * 64;
    const float* er = encs + r * 64;
#pragma unroll 8
    for (int k = 0; k < 64; ++k) y += er[k] * we[k];
    xnew[row * 128 + c] = y;

    // LayerNorm over the 128 c's of this row (2 waves per row)
    float s = y, q = y * y;
    for (int m = 32; m; m >>= 1) { s += __shfl_xor(s, m); q += __shfl_xor(q, m); }
    int wv = t >> 6;
    if ((t & 63) == 0) { red[0][wv] = s; red[1][wv] = q; }
    __syncthreads();
    float ssum = red[0][2 * r] + red[0][2 * r + 1];
    float qsum = red[1][2 * r] + red[1][2 * r + 1];
    float mean = ssum * (1.f / 128.f);
    float var = qsum * (1.f / 128.f) - mean * mean;
    float rstd = rsqrtf(var + EPS);
    float xn = (y - mean) * rstd * g1[c] + b1[c];
    xns[r * 128 + c] = xn;
    __syncthreads();

    const float* w0 = W0 + c * 128;
    const float* xr = xns + r * 128;
    float h = 0.f;
#pragma unroll 8
    for (int k = 0; k < 128; ++k) h += xr[k] * w0[k];
    hbf[row * 128 + c] = f2bf(h);

    float p1 = h * Wa[c], p2 = h * Wa[128 + c];
    for (int m = 32; m; m >>= 1) { p1 += __shfl_xor(p1, m); p2 += __shfl_xor(p2, m); }
    if ((t & 63) == 0) { red[2][wv] = p1; red[3][wv] = p2; }
    __syncthreads();
    if (c == 0) {
        s1[row] = red[2][2 * r] + red[2][2 * r + 1];
        s2[row] = red[3][2 * r] + red[3][2 * r + 1];
    }
}

// ---------------- Kernel T: transpose h (2048x128 bf16) -> hT (128x2048) ----
__global__ __launch_bounds__(256) void kT(const unsigned short* __restrict__ h,
                                          unsigned short* __restrict__ hT)
{
    int bid = blockIdx.x;
    int b = bid >> 6;           // 64 tiles (32 j-tiles x 2 c-tiles) per batch
    int tb = bid & 63;
    int jt = tb >> 1, ct = tb & 1;
    __shared__ unsigned short tile[64][65];
    int t = threadIdx.x;
    int col = t & 63, rg = t >> 6;
    const unsigned short* hb = h + (long long)b * 2048 * 128;
    unsigned short* hTb = hT + (long long)b * 128 * 2048;
#pragma unroll
    for (int rr = 0; rr < 16; ++rr) {
        int rowl = rg * 16 + rr;
        tile[rowl][col] = hb[(long long)(jt * 64 + rowl) * 128 + ct * 64 + col];
    }
    __syncthreads();
#pragma unroll
    for (int rr = 0; rr < 16; ++rr) {
        int crow = rg * 16 + rr;
        hTb[(long long)(ct * 64 + crow) * 2048 + jt * 64 + col] = tile[col][crow];
    }
}

// ---------------- Kernel C: per-row softmax constant C_i = m_i + log(l_i) ---
__global__ __launch_bounds__(256) void kC(const float* __restrict__ s1,
                                          const float* __restrict__ s2,
                                          float* __restrict__ Cc)
{
    int t = threadIdx.x;
    int w = t >> 6, lane = t & 63;
    long long row = (long long)blockIdx.x * 4 + w;
    int b = (int)(row >> 11);
    const float* s2b = s2 + (long long)b * 2048;
    float s1i = s1[row];

    float mx = -1e30f;
    for (int j = lane; j < 2048; j += 64) mx = fmaxf(mx, s2b[j]);
    for (int m = 32; m; m >>= 1) mx = fmaxf(mx, __shfl_xor(mx, m));
    float z0 = s1i + mx;
    float mi = fmaxf(z0, NSLOPE * z0);   // lrelu is monotone -> row max

    float l = 0.f;
    for (int j = lane; j < 2048; j += 64) {
        float z = s1i + s2b[j];
        float zl = fmaxf(z, NSLOPE * z);
        l += __expf(zl - mi);
    }
    for (int m = 32; m; m >>= 1) l += __shfl_xor(l, m);
    if (lane == 0) Cc[row] = mi + __logf(l);
}

// ---------------- Kernel D: write atten (f32) + attentioned = atten @ h -----
// block = 4 waves; wave w: i-strip = btile*32 + (w&1)*16, c-half = (w>>1)*64
__global__ __launch_bounds__(256) void kD(
    const float* __restrict__ s1, const float* __restrict__ s2,
    const float* __restrict__ Cc, const unsigned short* __restrict__ hT,
    float* __restrict__ atten, float* __restrict__ attn)
{
    int t = threadIdx.x;
    int w = t >> 6, lane = t & 63;
    int b = blockIdx.x >> 6;     // 64 i-tiles (32 rows each) per batch
    int it = blockIdx.x & 63;
    int i0 = it * 32 + (w & 1) * 16;
    int chalf = (w >> 1) * 64;
    int ml = lane & 15, quad = lane >> 4;

    long long gi = (long long)b * 2048 + i0 + ml;
    float s1i = s1[gi];
    float Ci = Cc[gi];
    const float* s2b = s2 + (long long)b * 2048;
    const unsigned short* hTb = hT + (long long)b * 128 * 2048;
    float* arow = atten + ((long long)b * 2048 + (i0 + ml)) * 2048;

    f32x4 acc[4] = {};
    for (int j0 = 0; j0 < 2048; j0 += 32) {
        int jb = j0 + quad * 8;
        float4 sa = *(const float4*)(s2b + jb);
        float4 sb = *(const float4*)(s2b + jb + 4);
        float zs[8] = {sa.x, sa.y, sa.z, sa.w, sb.x, sb.y, sb.z, sb.w};
        float p[8];
        BF8 af;
#pragma unroll
        for (int k = 0; k < 8; ++k) {
            float z = s1i + zs[k];
            float zl = fmaxf(z, NSLOPE * z);
            p[k] = __expf(zl - Ci);          // = exp(lrelu-m)/l
            af.u[k] = f2bf(p[k]);
        }
        // exact f32 softmax row out (only c-half 0 wave-pair would duplicate:
        // waves with chalf==64 write the same values to the same addresses ->
        // benign duplicate; avoid it by letting only chalf==0 waves write
        if (chalf == 0) {
            *(float4*)(arow + jb) = make_float4(p[0], p[1], p[2], p[3]);
            *(float4*)(arow + jb + 4) = make_float4(p[4], p[5], p[6], p[7]);
        }
#pragma unroll
        for (int ct = 0; ct < 4; ++ct) {
            int cc = chalf + ct * 16 + ml;
            s16x8 bfrag = *(const s16x8*)(hTb + (long long)cc * 2048 + jb);
            acc[ct] = __builtin_amdgcn_mfma_f32_16x16x32_bf16(af.v, bfrag, acc[ct], 0, 0, 0);
        }
    }
#pragma unroll
    for (int ct = 0; ct < 4; ++ct) {
#pragma unroll
        for (int rg = 0; rg < 4; ++rg) {
            int ii = i0 + quad * 4 + rg;
            int cc = chalf + ct * 16 + ml;
            attn[((long long)b * 2048 + ii) * 128 + cc] = acc[ct][rg];
        }
    }
}

// ---------------- Kernel E: residual + LN2 + W1^T + elu (in-place on d_out) -
__global__ __launch_bounds__(256) void kE(
    const float* __restrict__ xnew, const float* __restrict__ g2,
    const float* __restrict__ b2, const float* __restrict__ W1,
    float* __restrict__ io)
{
    int t = threadIdx.x;
    int r = t >> 7, c = t & 127;
    long long row = (long long)blockIdx.x * 2 + r;
    __shared__ float xns[2 * 128];
    __shared__ float red[2][4];

    float a = io[row * 128 + c] + xnew[row * 128 + c];
    float s = a, q = a * a;
    for (int m = 32; m; m >>= 1) { s += __shfl_xor(s, m); q += __shfl_xor(q, m); }
    int wv = t >> 6;
    if ((t & 63) == 0) { red[0][wv] = s; red[1][wv] = q; }
    __syncthreads();
    float ssum = red[0][2 * r] + red[0][2 * r + 1];
    float qsum = red[1][2 * r] + red[1][2 * r + 1];
    float mean = ssum * (1.f / 128.f);
    float var = qsum * (1.f / 128.f) - mean * mean;
    float rstd = rsqrtf(var + EPS);
    float xn = (a - mean) * rstd * g2[c] + b2[c];
    xns[r * 128 + c] = xn;
    __syncthreads();

    const float* w1 = W1 + c * 128;
    const float* xr = xns + r * 128;
    float hv = 0.f;
#pragma unroll 8
    for (int k = 0; k < 128; ++k) hv += xr[k] * w1[k];
    float out = hv > 0.f ? hv : (__expf(hv) - 1.f);   // elu, alpha=1
    io[row * 128 + c] = out;
}

extern "C" void kernel_launch(void* const* d_in, const int* in_sizes, int n_in,
                              void* d_out, int out_size, void* d_ws, size_t ws_size,
                              hipStream_t stream)
{
    const float* x     = (const float*)d_in[0];
    const float* enc   = (const float*)d_in[1];
    const float* W_enc = (const float*)d_in[2];
    const float* b_enc = (const float*)d_in[3];
    const float* g1    = (const float*)d_in[4];
    const float* b1    = (const float*)d_in[5];
    const float* g2    = (const float*)d_in[6];
    const float* b2    = (const float*)d_in[7];
    const float* W0    = (const float*)d_in[8];
    const float* Wa    = (const float*)d_in[9];
    const float* W1    = (const float*)d_in[10];

    float* out = (float*)d_out;
    const long long ROWS = 8LL * 2048;          // 16384
    const long long HN   = ROWS * 128;          // 2097152 (h_next elements)

    // workspace layout (floats)
    float* xnew = (float*)d_ws;                 // 2097152
    float* s1   = xnew + HN;                    // 16384
    float* s2   = s1 + ROWS;                    // 16384
    float* Cc   = s2 + ROWS;                    // 16384
    unsigned short* hbf = (unsigned short*)(Cc + ROWS);   // 2097152 bf16
    unsigned short* hT  = hbf + HN;                       // 2097152 bf16

    float* atten = out + HN;        // 8*2048*2048 f32 output region
    float* attn  = out;             // attentioned parked in h_next region

    kA<<<8192, 256, 0, stream>>>(x, enc, W_enc, b_enc, g1, b1, W0, Wa,
                                 xnew, hbf, s1, s2);
    kT<<<512, 256, 0, stream>>>(hbf, hT);
    kC<<<4096, 256, 0, stream>>>(s1, s2, Cc);
    kD<<<512, 256, 0, stream>>>(s1, s2, Cc, hT, atten, attn);
    kE<<<8192, 256, 0, stream>>>(xnew, g2, b2, W1, out);
}

// Round 2
// 529.179 us; speedup vs baseline: 1.0584x; 1.0584x over previous
//
#include <hip/hip_runtime.h>
#include <hip/hip_bf16.h>
#include <cstddef>

#define EPS 1e-5f
#define NSLOPE 0.01f

typedef __attribute__((ext_vector_type(8))) short s16x8;   // 8 bf16 (4 VGPRs)
typedef __attribute__((ext_vector_type(4))) float f32x4;

union BF8 { unsigned short u[8]; s16x8 v; };

static __device__ inline unsigned short f2bf(float f) {
    unsigned int u = __float_as_uint(f);
    u += 0x7fffu + ((u >> 16) & 1u);   // round-to-nearest-even
    return (unsigned short)(u >> 16);
}

// ---------------- Kernel W: pack transposed weights as float2 ---------------
// WeP[k*64+l] = (W_enc[l][k], W_enc[l+64][k])      k<64
// W0P[k*64+l] = (W0[l][k],    W0[l+64][k])         k<128
// W1P[k*64+l] = (W1[l][k],    W1[l+64][k])         k<128
__global__ __launch_bounds__(256) void kW(
    const float* __restrict__ W_enc, const float* __restrict__ W0,
    const float* __restrict__ W1,
    float2* __restrict__ WeP, float2* __restrict__ W0P, float2* __restrict__ W1P)
{
    int idx = blockIdx.x * 256 + threadIdx.x;
    if (idx < 64 * 64) {
        int k = idx >> 6, l = idx & 63;
        WeP[idx] = make_float2(W_enc[l * 64 + k], W_enc[(l + 64) * 64 + k]);
    }
    int i0 = idx - 64 * 64;
    if (i0 >= 0 && i0 < 128 * 64) {
        int k = i0 >> 6, l = i0 & 63;
        W0P[i0] = make_float2(W0[l * 128 + k], W0[(l + 64) * 128 + k]);
    }
    int i1 = idx - 64 * 64 - 128 * 64;
    if (i1 >= 0 && i1 < 128 * 64) {
        int k = i1 >> 6, l = i1 & 63;
        W1P[i1] = make_float2(W1[l * 128 + k], W1[(l + 64) * 128 + k]);
    }
}

// ---------------- Kernel A: x+=enc@W_enc^T+b_enc; LN1; h=xn@W0^T; s1,s2 ----
// 16 rows/block; wave w owns rows w*4..w*4+3; lane l owns cols l, l+64.
__global__ __launch_bounds__(256) void kA(
    const float* __restrict__ x, const float* __restrict__ enc,
    const float2* __restrict__ WeP, const float* __restrict__ b_enc,
    const float* __restrict__ g1, const float* __restrict__ b1,
    const float2* __restrict__ W0P, const float* __restrict__ Wa,
    float* __restrict__ xnew, unsigned short* __restrict__ hbf,
    float* __restrict__ s1, float* __restrict__ s2)
{
    int t = threadIdx.x;
    int w = t >> 6, l = t & 63;
    long long row0 = (long long)blockIdx.x * 16 + w * 4;

    float be0 = b_enc[l], be1 = b_enc[l + 64];
    float er[4], y0[4], y1[4];
#pragma unroll
    for (int r = 0; r < 4; ++r) {
        long long row = row0 + r;
        er[r] = enc[row * 64 + l];
        y0[r] = x[row * 128 + l] + be0;
        y1[r] = x[row * 128 + l + 64] + be1;
    }
#pragma unroll
    for (int k = 0; k < 64; ++k) {
        float2 wv = WeP[k * 64 + l];
#pragma unroll
        for (int r = 0; r < 4; ++r) {
            float ek = __shfl(er[r], k, 64);
            y0[r] = fmaf(ek, wv.x, y0[r]);
            y1[r] = fmaf(ek, wv.y, y1[r]);
        }
    }
    float g1a = g1[l], g1b = g1[l + 64], b1a = b1[l], b1b = b1[l + 64];
    float xn0[4], xn1[4];
#pragma unroll
    for (int r = 0; r < 4; ++r) {
        long long row = row0 + r;
        xnew[row * 128 + l] = y0[r];
        xnew[row * 128 + l + 64] = y1[r];
        float s = y0[r] + y1[r];
        float q = y0[r] * y0[r] + y1[r] * y1[r];
#pragma unroll
        for (int m = 32; m; m >>= 1) { s += __shfl_xor(s, m); q += __shfl_xor(q, m); }
        float mean = s * (1.f / 128.f);
        float var = q * (1.f / 128.f) - mean * mean;
        float rstd = rsqrtf(var + EPS);
        xn0[r] = (y0[r] - mean) * rstd * g1a + b1a;
        xn1[r] = (y1[r] - mean) * rstd * g1b + b1b;
    }
    float h0[4] = {0.f, 0.f, 0.f, 0.f}, h1[4] = {0.f, 0.f, 0.f, 0.f};
#pragma unroll
    for (int k = 0; k < 64; ++k) {
        float2 wv  = W0P[k * 64 + l];
        float2 wv2 = W0P[(k + 64) * 64 + l];
#pragma unroll
        for (int r = 0; r < 4; ++r) {
            float a = __shfl(xn0[r], k, 64);
            float b = __shfl(xn1[r], k, 64);
            h0[r] = fmaf(a, wv.x, h0[r]);
            h1[r] = fmaf(a, wv.y, h1[r]);
            h0[r] = fmaf(b, wv2.x, h0[r]);
            h1[r] = fmaf(b, wv2.y, h1[r]);
        }
    }
    float a1a = Wa[l], a1b = Wa[l + 64], a2a = Wa[128 + l], a2b = Wa[192 + l];
#pragma unroll
    for (int r = 0; r < 4; ++r) {
        long long row = row0 + r;
        hbf[row * 128 + l]      = f2bf(h0[r]);
        hbf[row * 128 + l + 64] = f2bf(h1[r]);
        float p1 = h0[r] * a1a + h1[r] * a1b;
        float p2 = h0[r] * a2a + h1[r] * a2b;
#pragma unroll
        for (int m = 32; m; m >>= 1) { p1 += __shfl_xor(p1, m); p2 += __shfl_xor(p2, m); }
        if (l == 0) { s1[row] = p1; s2[row] = p2; }
    }
}

// ---------------- Kernel T: transpose h (2048x128 bf16) -> hT (128x2048) ----
__global__ __launch_bounds__(256) void kT(const unsigned short* __restrict__ h,
                                          unsigned short* __restrict__ hT)
{
    int bid = blockIdx.x;
    int b = bid >> 6;           // 64 tiles (32 j-tiles x 2 c-tiles) per batch
    int tb = bid & 63;
    int jt = tb >> 1, ct = tb & 1;
    __shared__ unsigned short tile[64][65];
    int t = threadIdx.x;
    int col = t & 63, rg = t >> 6;
    const unsigned short* hb = h + (long long)b * 2048 * 128;
    unsigned short* hTb = hT + (long long)b * 128 * 2048;
#pragma unroll
    for (int rr = 0; rr < 16; ++rr) {
        int rowl = rg * 16 + rr;
        tile[rowl][col] = hb[(long long)(jt * 64 + rowl) * 128 + ct * 64 + col];
    }
    __syncthreads();
#pragma unroll
    for (int rr = 0; rr < 16; ++rr) {
        int crow = rg * 16 + rr;
        hTb[(long long)(ct * 64 + crow) * 2048 + jt * 64 + col] = tile[col][crow];
    }
}

// ---------------- Kernel C: per-row softmax constant C_i = m_i + log(l_i) ---
__global__ __launch_bounds__(256) void kC(const float* __restrict__ s1,
                                          const float* __restrict__ s2,
                                          float* __restrict__ Cc)
{
    int t = threadIdx.x;
    int w = t >> 6, lane = t & 63;
    long long row = (long long)blockIdx.x * 4 + w;
    int b = (int)(row >> 11);
    const float* s2b = s2 + (long long)b * 2048;
    float s1i = s1[row];

    float mx = -1e30f;
    for (int j = lane; j < 2048; j += 64) mx = fmaxf(mx, s2b[j]);
    for (int m = 32; m; m >>= 1) mx = fmaxf(mx, __shfl_xor(mx, m));
    float z0 = s1i + mx;
    float mi = fmaxf(z0, NSLOPE * z0);   // lrelu is monotone -> row max

    float l = 0.f;
    for (int j = lane; j < 2048; j += 64) {
        float z = s1i + s2b[j];
        float zl = fmaxf(z, NSLOPE * z);
        l += __expf(zl - mi);
    }
    for (int m = 32; m; m >>= 1) l += __shfl_xor(l, m);
    if (lane == 0) Cc[row] = mi + __logf(l);
}

// ---------------- Kernel D: write atten (f32) + attentioned = atten @ h -----
// block = 4 waves; wave w: i-strip = btile*32 + (w&1)*16, c-half = (w>>1)*64
__global__ __launch_bounds__(256) void kD(
    const float* __restrict__ s1, const float* __restrict__ s2,
    const float* __restrict__ Cc, const unsigned short* __restrict__ hT,
    float* __restrict__ atten, float* __restrict__ attn)
{
    int t = threadIdx.x;
    int w = t >> 6, lane = t & 63;
    int b = blockIdx.x >> 6;     // 64 i-tiles (32 rows each) per batch
    int it = blockIdx.x & 63;
    int i0 = it * 32 + (w & 1) * 16;
    int chalf = (w >> 1) * 64;
    int ml = lane & 15, quad = lane >> 4;

    long long gi = (long long)b * 2048 + i0 + ml;
    float s1i = s1[gi];
    float Ci = Cc[gi];
    const float* s2b = s2 + (long long)b * 2048;
    const unsigned short* hTb = hT + (long long)b * 128 * 2048;
    float* arow = atten + ((long long)b * 2048 + (i0 + ml)) * 2048;

    f32x4 acc[4] = {};
    for (int j0 = 0; j0 < 2048; j0 += 32) {
        int jb = j0 + quad * 8;
        float4 sa = *(const float4*)(s2b + jb);
        float4 sb = *(const float4*)(s2b + jb + 4);
        float zs[8] = {sa.x, sa.y, sa.z, sa.w, sb.x, sb.y, sb.z, sb.w};
        float p[8];
        BF8 af;
#pragma unroll
        for (int k = 0; k < 8; ++k) {
            float z = s1i + zs[k];
            float zl = fmaxf(z, NSLOPE * z);
            p[k] = __expf(zl - Ci);          // = exp(lrelu-m)/l
            af.u[k] = f2bf(p[k]);
        }
        if (chalf == 0) {
            *(float4*)(arow + jb) = make_float4(p[0], p[1], p[2], p[3]);
            *(float4*)(arow + jb + 4) = make_float4(p[4], p[5], p[6], p[7]);
        }
#pragma unroll
        for (int ct = 0; ct < 4; ++ct) {
            int cc = chalf + ct * 16 + ml;
            s16x8 bfrag = *(const s16x8*)(hTb + (long long)cc * 2048 + jb);
            acc[ct] = __builtin_amdgcn_mfma_f32_16x16x32_bf16(af.v, bfrag, acc[ct], 0, 0, 0);
        }
    }
#pragma unroll
    for (int ct = 0; ct < 4; ++ct) {
#pragma unroll
        for (int rg = 0; rg < 4; ++rg) {
            int ii = i0 + quad * 4 + rg;
            int cc = chalf + ct * 16 + ml;
            attn[((long long)b * 2048 + ii) * 128 + cc] = acc[ct][rg];
        }
    }
}

// ---------------- Kernel E: residual + LN2 + W1^T + elu (in-place on d_out) -
// Same structure as kA: 16 rows/block, wave owns 4 rows, lane owns 2 cols.
__global__ __launch_bounds__(256) void kE(
    const float* __restrict__ xnew, const float* __restrict__ g2,
    const float* __restrict__ b2, const float2* __restrict__ W1P,
    float* __restrict__ io)
{
    int t = threadIdx.x;
    int w = t >> 6, l = t & 63;
    long long row0 = (long long)blockIdx.x * 16 + w * 4;

    float a0[4], a1v[4];
#pragma unroll
    for (int r = 0; r < 4; ++r) {
        long long row = row0 + r;
        a0[r]  = io[row * 128 + l]      + xnew[row * 128 + l];
        a1v[r] = io[row * 128 + l + 64] + xnew[row * 128 + l + 64];
    }
    float g2a = g2[l], g2b = g2[l + 64], b2a = b2[l], b2b = b2[l + 64];
    float xn0[4], xn1[4];
#pragma unroll
    for (int r = 0; r < 4; ++r) {
        float s = a0[r] + a1v[r];
        float q = a0[r] * a0[r] + a1v[r] * a1v[r];
#pragma unroll
        for (int m = 32; m; m >>= 1) { s += __shfl_xor(s, m); q += __shfl_xor(q, m); }
        float mean = s * (1.f / 128.f);
        float var = q * (1.f / 128.f) - mean * mean;
        float rstd = rsqrtf(var + EPS);
        xn0[r] = (a0[r] - mean) * rstd * g2a + b2a;
        xn1[r] = (a1v[r] - mean) * rstd * g2b + b2b;
    }
    float h0[4] = {0.f, 0.f, 0.f, 0.f}, h1[4] = {0.f, 0.f, 0.f, 0.f};
#pragma unroll
    for (int k = 0; k < 64; ++k) {
        float2 wv  = W1P[k * 64 + l];
        float2 wv2 = W1P[(k + 64) * 64 + l];
#pragma unroll
        for (int r = 0; r < 4; ++r) {
            float a = __shfl(xn0[r], k, 64);
            float b = __shfl(xn1[r], k, 64);
            h0[r] = fmaf(a, wv.x, h0[r]);
            h1[r] = fmaf(a, wv.y, h1[r]);
            h0[r] = fmaf(b, wv2.x, h0[r]);
            h1[r] = fmaf(b, wv2.y, h1[r]);
        }
    }
#pragma unroll
    for (int r = 0; r < 4; ++r) {
        long long row = row0 + r;
        float v0 = h0[r] > 0.f ? h0[r] : (__expf(h0[r]) - 1.f);
        float v1 = h1[r] > 0.f ? h1[r] : (__expf(h1[r]) - 1.f);
        io[row * 128 + l]      = v0;
        io[row * 128 + l + 64] = v1;
    }
}

extern "C" void kernel_launch(void* const* d_in, const int* in_sizes, int n_in,
                              void* d_out, int out_size, void* d_ws, size_t ws_size,
                              hipStream_t stream)
{
    const float* x     = (const float*)d_in[0];
    const float* enc   = (const float*)d_in[1];
    const float* W_enc = (const float*)d_in[2];
    const float* b_enc = (const float*)d_in[3];
    const float* g1    = (const float*)d_in[4];
    const float* b1    = (const float*)d_in[5];
    const float* g2    = (const float*)d_in[6];
    const float* b2    = (const float*)d_in[7];
    const float* W0    = (const float*)d_in[8];
    const float* Wa    = (const float*)d_in[9];
    const float* W1    = (const float*)d_in[10];

    float* out = (float*)d_out;
    const long long ROWS = 8LL * 2048;          // 16384
    const long long HN   = ROWS * 128;          // 2097152 (h_next elements)

    // workspace layout (floats)
    float* xnew = (float*)d_ws;                 // 2097152
    float* s1   = xnew + HN;                    // 16384
    float* s2   = s1 + ROWS;                    // 16384
    float* Cc   = s2 + ROWS;                    // 16384
    unsigned short* hbf = (unsigned short*)(Cc + ROWS);   // 2097152 bf16
    unsigned short* hT  = hbf + HN;                       // 2097152 bf16
    float2* WeP = (float2*)(hT + HN);           // 4096 float2
    float2* W0P = WeP + 64 * 64;                // 8192 float2
    float2* W1P = W0P + 128 * 64;               // 8192 float2

    float* atten = out + HN;        // 8*2048*2048 f32 output region
    float* attn  = out;             // attentioned parked in h_next region

    kW<<<80, 256, 0, stream>>>(W_enc, W0, W1, WeP, W0P, W1P);
    kA<<<1024, 256, 0, stream>>>(x, enc, WeP, b_enc, g1, b1, W0P, Wa,
                                 xnew, hbf, s1, s2);
    kT<<<512, 256, 0, stream>>>(hbf, hT);
    kC<<<4096, 256, 0, stream>>>(s1, s2, Cc);
    kD<<<512, 256, 0, stream>>>(s1, s2, Cc, hT, atten, attn);
    kE<<<1024, 256, 0, stream>>>(xnew, g2, b2, W1P, out);
}

// Round 3
// 277.306 us; speedup vs baseline: 2.0197x; 1.9083x over previous
//
#include <hip/hip_runtime.h>
#include <hip/hip_bf16.h>
#include <cstddef>

#define EPS 1e-5f
#define NSLOPE 0.01f

typedef __attribute__((ext_vector_type(8))) short s16x8;   // 8 bf16 (4 VGPRs)
typedef __attribute__((ext_vector_type(4))) float f32x4;

union BF8 { unsigned short u[8]; s16x8 v; };

static __device__ inline unsigned short f2bf(float f) {
    unsigned int u = __float_as_uint(f);
    u += 0x7fffu + ((u >> 16) & 1u);   // round-to-nearest-even
    return (unsigned short)(u >> 16);
}

// ---------------- Kernel W: cast weights to bf16 row-major -----------------
// Web[n*64+k]  = bf16(W_enc[n][k])   (B-frag layout for GEMM1)
// W0b[n*128+k] = bf16(W0[n][k])      (B-frag layout for GEMM2)
// W1b[n*128+k] = bf16(W1[n][k])      (B-frag layout for kE GEMM)
__global__ __launch_bounds__(256) void kW(
    const float* __restrict__ W_enc, const float* __restrict__ W0,
    const float* __restrict__ W1,
    unsigned short* __restrict__ Web, unsigned short* __restrict__ W0b,
    unsigned short* __restrict__ W1b)
{
    int idx = blockIdx.x * 256 + threadIdx.x;
    if (idx < 128 * 64) Web[idx] = f2bf(W_enc[idx]);
    if (idx < 128 * 128) { W0b[idx] = f2bf(W0[idx]); W1b[idx] = f2bf(W1[idx]); }
}

// ---------------- Kernel A -------------------------------------------------
// 32 rows/block. 4 waves: w&1 -> 16-row strip, w>>1 -> 64-col half.
// GEMM1 (enc@WencT,K=64,MFMA) -> +x+b_enc -> LN1 -> GEMM2 (xn@W0T,K=128)
// -> s1,s2 row-dots; hT written via LDS transpose (replaces old kT kernel).
__global__ __launch_bounds__(256, 4) void kA(
    const float* __restrict__ x, const float* __restrict__ enc,
    const unsigned short* __restrict__ Web, const float* __restrict__ b_enc,
    const float* __restrict__ g1, const float* __restrict__ b1,
    const unsigned short* __restrict__ W0b, const float* __restrict__ Wa,
    float* __restrict__ xnew, unsigned short* __restrict__ hT,
    float* __restrict__ s1, float* __restrict__ s2)
{
    __shared__ float ys[32][132];             // y rows (f32) for LN
    __shared__ unsigned short xnb[32][136];   // LN output (bf16) A-frags
    __shared__ unsigned short hts[128][40];   // h transposed (bf16)
    __shared__ float ps1[2][32], ps2[2][32];  // s1/s2 partials per col-half

    int t = threadIdx.x;
    int w = t >> 6, lane = t & 63;
    int ml = lane & 15, quad = lane >> 4;
    int mrow = (w & 1) * 16;
    int chalf = (w >> 1) * 64;
    long long R0 = (long long)blockIdx.x * 32;
    int b = (int)(R0 >> 11);
    int j0 = (int)(R0 & 2047);

    // ---- GEMM1: acc1 = enc @ WencT (K=64) ----
    f32x4 acc1[4] = {};
    const float* encrow = enc + (R0 + mrow + ml) * 64 + quad * 8;
#pragma unroll
    for (int kb = 0; kb < 2; ++kb) {
        float4 e0 = *(const float4*)(encrow + kb * 32);
        float4 e1 = *(const float4*)(encrow + kb * 32 + 4);
        BF8 af;
        af.u[0] = f2bf(e0.x); af.u[1] = f2bf(e0.y);
        af.u[2] = f2bf(e0.z); af.u[3] = f2bf(e0.w);
        af.u[4] = f2bf(e1.x); af.u[5] = f2bf(e1.y);
        af.u[6] = f2bf(e1.z); af.u[7] = f2bf(e1.w);
#pragma unroll
        for (int ct = 0; ct < 4; ++ct) {
            int n = chalf + ct * 16 + ml;
            s16x8 bf = *(const s16x8*)(Web + n * 64 + kb * 32 + quad * 8);
            acc1[ct] = __builtin_amdgcn_mfma_f32_16x16x32_bf16(af.v, bf, acc1[ct], 0, 0, 0);
        }
    }
    // epilogue: y = acc1 + x + b_enc -> xnew, ys
#pragma unroll
    for (int ct = 0; ct < 4; ++ct) {
        int col = chalf + ct * 16 + ml;
        float be = b_enc[col];
#pragma unroll
        for (int rg = 0; rg < 4; ++rg) {
            int rl = mrow + quad * 4 + rg;
            long long row = R0 + rl;
            float y = acc1[ct][rg] + x[row * 128 + col] + be;
            xnew[row * 128 + col] = y;
            ys[rl][col] = y;
        }
    }
    __syncthreads();

    // ---- LN1: 8 threads per row ----
    {
        int rl = t >> 3, sub = t & 7;
        float v[16];
        float s = 0.f, q = 0.f;
#pragma unroll
        for (int i = 0; i < 16; ++i) {
            v[i] = ys[rl][sub * 16 + i];
            s += v[i]; q += v[i] * v[i];
        }
#pragma unroll
        for (int m = 1; m < 8; m <<= 1) { s += __shfl_xor(s, m); q += __shfl_xor(q, m); }
        float mean = s * (1.f / 128.f);
        float var = q * (1.f / 128.f) - mean * mean;
        float rstd = rsqrtf(var + EPS);
#pragma unroll
        for (int i = 0; i < 16; ++i) {
            int col = sub * 16 + i;
            float xn = (v[i] - mean) * rstd * g1[col] + b1[col];
            xnb[rl][col] = f2bf(xn);
        }
    }
    __syncthreads();

    // ---- GEMM2: h = xn @ W0T (K=128) ----
    f32x4 acc2[4] = {};
#pragma unroll
    for (int kb = 0; kb < 4; ++kb) {
        s16x8 af = *(const s16x8*)(&xnb[mrow + ml][kb * 32 + quad * 8]);
#pragma unroll
        for (int ct = 0; ct < 4; ++ct) {
            int n = chalf + ct * 16 + ml;
            s16x8 bf = *(const s16x8*)(W0b + n * 128 + kb * 32 + quad * 8);
            acc2[ct] = __builtin_amdgcn_mfma_f32_16x16x32_bf16(af, bf, acc2[ct], 0, 0, 0);
        }
    }

    // ---- epilogue: hT stash + s1/s2 partial dots ----
#pragma unroll
    for (int ct = 0; ct < 4; ++ct) {
        int col = chalf + ct * 16 + ml;
#pragma unroll
        for (int rg = 0; rg < 4; ++rg)
            hts[col][mrow + quad * 4 + rg] = f2bf(acc2[ct][rg]);
    }
#pragma unroll
    for (int rg = 0; rg < 4; ++rg) {
        float p1 = 0.f, p2 = 0.f;
#pragma unroll
        for (int ct = 0; ct < 4; ++ct) {
            int col = chalf + ct * 16 + ml;
            p1 += acc2[ct][rg] * Wa[col];
            p2 += acc2[ct][rg] * Wa[128 + col];
        }
#pragma unroll
        for (int m = 1; m < 16; m <<= 1) { p1 += __shfl_xor(p1, m); p2 += __shfl_xor(p2, m); }
        if (ml == 0) {
            int rl = mrow + quad * 4 + rg;
            ps1[w >> 1][rl] = p1;
            ps2[w >> 1][rl] = p2;
        }
    }
    __syncthreads();
    if (t < 32) {
        s1[R0 + t] = ps1[0][t] + ps1[1][t];
        s2[R0 + t] = ps2[0][t] + ps2[1][t];
    }
    // coalesced hT store: thread -> (col, 16-j half)
    {
        int c = t >> 1, half = t & 1;
        unsigned short* dst = hT + ((long long)b * 128 + c) * 2048 + j0 + half * 16;
        const unsigned short* srcp = &hts[c][half * 16];
        *(s16x8*)(dst) = *(const s16x8*)(srcp);
        *(s16x8*)(dst + 8) = *(const s16x8*)(srcp + 8);
    }
}

// ---------------- Kernel C: per-row softmax constant C_i = m_i + log(l_i) ---
__global__ __launch_bounds__(256) void kC(const float* __restrict__ s1,
                                          const float* __restrict__ s2,
                                          float* __restrict__ Cc)
{
    int t = threadIdx.x;
    int w = t >> 6, lane = t & 63;
    long long row = (long long)blockIdx.x * 4 + w;
    int b = (int)(row >> 11);
    const float* s2b = s2 + (long long)b * 2048;
    float s1i = s1[row];

    float mx = -1e30f;
    for (int j = lane; j < 2048; j += 64) mx = fmaxf(mx, s2b[j]);
    for (int m = 32; m; m >>= 1) mx = fmaxf(mx, __shfl_xor(mx, m));
    float z0 = s1i + mx;
    float mi = fmaxf(z0, NSLOPE * z0);   // lrelu is monotone -> row max

    float l = 0.f;
    for (int j = lane; j < 2048; j += 64) {
        float z = s1i + s2b[j];
        float zl = fmaxf(z, NSLOPE * z);
        l += __expf(zl - mi);
    }
    for (int m = 32; m; m >>= 1) l += __shfl_xor(l, m);
    if (lane == 0) Cc[row] = mi + __logf(l);
}

// ---------------- Kernel D: write atten (f32) + attentioned = atten @ h -----
__global__ __launch_bounds__(256) void kD(
    const float* __restrict__ s1, const float* __restrict__ s2,
    const float* __restrict__ Cc, const unsigned short* __restrict__ hT,
    float* __restrict__ atten, float* __restrict__ attn)
{
    int t = threadIdx.x;
    int w = t >> 6, lane = t & 63;
    int b = blockIdx.x >> 6;     // 64 i-tiles (32 rows each) per batch
    int it = blockIdx.x & 63;
    int i0 = it * 32 + (w & 1) * 16;
    int chalf = (w >> 1) * 64;
    int ml = lane & 15, quad = lane >> 4;

    long long gi = (long long)b * 2048 + i0 + ml;
    float s1i = s1[gi];
    float Ci = Cc[gi];
    const float* s2b = s2 + (long long)b * 2048;
    const unsigned short* hTb = hT + (long long)b * 128 * 2048;
    float* arow = atten + ((long long)b * 2048 + (i0 + ml)) * 2048;

    f32x4 acc[4] = {};
    for (int j0j = 0; j0j < 2048; j0j += 32) {
        int jb = j0j + quad * 8;
        float4 sa = *(const float4*)(s2b + jb);
        float4 sb = *(const float4*)(s2b + jb + 4);
        float zs[8] = {sa.x, sa.y, sa.z, sa.w, sb.x, sb.y, sb.z, sb.w};
        float p[8];
        BF8 af;
#pragma unroll
        for (int k = 0; k < 8; ++k) {
            float z = s1i + zs[k];
            float zl = fmaxf(z, NSLOPE * z);
            p[k] = __expf(zl - Ci);          // = exp(lrelu-m)/l
            af.u[k] = f2bf(p[k]);
        }
        if (chalf == 0) {
            *(float4*)(arow + jb) = make_float4(p[0], p[1], p[2], p[3]);
            *(float4*)(arow + jb + 4) = make_float4(p[4], p[5], p[6], p[7]);
        }
#pragma unroll
        for (int ct = 0; ct < 4; ++ct) {
            int cc = chalf + ct * 16 + ml;
            s16x8 bfrag = *(const s16x8*)(hTb + (long long)cc * 2048 + jb);
            acc[ct] = __builtin_amdgcn_mfma_f32_16x16x32_bf16(af.v, bfrag, acc[ct], 0, 0, 0);
        }
    }
#pragma unroll
    for (int ct = 0; ct < 4; ++ct) {
#pragma unroll
        for (int rg = 0; rg < 4; ++rg) {
            int ii = i0 + quad * 4 + rg;
            int cc = chalf + ct * 16 + ml;
            attn[((long long)b * 2048 + ii) * 128 + cc] = acc[ct][rg];
        }
    }
}

// ---------------- Kernel E: residual + LN2 + W1^T + elu (in-place) ---------
// 32 rows/block; LN inline (coalesced loads), then MFMA GEMM K=128.
__global__ __launch_bounds__(256, 4) void kE(
    const float* __restrict__ xnew, const float* __restrict__ g2,
    const float* __restrict__ b2, const unsigned short* __restrict__ W1b,
    float* __restrict__ io)
{
    __shared__ unsigned short xnb[32][136];
    int t = threadIdx.x;
    long long R0 = (long long)blockIdx.x * 32;

    {
        int rl = t >> 3, sub = t & 7;
        long long row = R0 + rl;
        const float* pio = io + row * 128 + sub * 16;
        const float* pxn = xnew + row * 128 + sub * 16;
        float v[16];
        float s = 0.f, q = 0.f;
#pragma unroll
        for (int i = 0; i < 16; i += 4) {
            float4 a = *(const float4*)(pio + i);
            float4 c = *(const float4*)(pxn + i);
            v[i]     = a.x + c.x; v[i + 1] = a.y + c.y;
            v[i + 2] = a.z + c.z; v[i + 3] = a.w + c.w;
        }
#pragma unroll
        for (int i = 0; i < 16; ++i) { s += v[i]; q += v[i] * v[i]; }
#pragma unroll
        for (int m = 1; m < 8; m <<= 1) { s += __shfl_xor(s, m); q += __shfl_xor(q, m); }
        float mean = s * (1.f / 128.f);
        float var = q * (1.f / 128.f) - mean * mean;
        float rstd = rsqrtf(var + EPS);
#pragma unroll
        for (int i = 0; i < 16; ++i) {
            int col = sub * 16 + i;
            float xn = (v[i] - mean) * rstd * g2[col] + b2[col];
            xnb[rl][col] = f2bf(xn);
        }
    }
    __syncthreads();

    int w = t >> 6, lane = t & 63;
    int ml = lane & 15, quad = lane >> 4;
    int mrow = (w & 1) * 16;
    int chalf = (w >> 1) * 64;

    f32x4 acc[4] = {};
#pragma unroll
    for (int kb = 0; kb < 4; ++kb) {
        s16x8 af = *(const s16x8*)(&xnb[mrow + ml][kb * 32 + quad * 8]);
#pragma unroll
        for (int ct = 0; ct < 4; ++ct) {
            int n = chalf + ct * 16 + ml;
            s16x8 bf = *(const s16x8*)(W1b + n * 128 + kb * 32 + quad * 8);
            acc[ct] = __builtin_amdgcn_mfma_f32_16x16x32_bf16(af, bf, acc[ct], 0, 0, 0);
        }
    }
#pragma unroll
    for (int ct = 0; ct < 4; ++ct) {
        int col = chalf + ct * 16 + ml;
#pragma unroll
        for (int rg = 0; rg < 4; ++rg) {
            int rl = mrow + quad * 4 + rg;
            float h = acc[ct][rg];
            float o = h > 0.f ? h : (__expf(h) - 1.f);
            io[(R0 + rl) * 128 + col] = o;
        }
    }
}

extern "C" void kernel_launch(void* const* d_in, const int* in_sizes, int n_in,
                              void* d_out, int out_size, void* d_ws, size_t ws_size,
                              hipStream_t stream)
{
    const float* x     = (const float*)d_in[0];
    const float* enc   = (const float*)d_in[1];
    const float* W_enc = (const float*)d_in[2];
    const float* b_enc = (const float*)d_in[3];
    const float* g1    = (const float*)d_in[4];
    const float* b1    = (const float*)d_in[5];
    const float* g2    = (const float*)d_in[6];
    const float* b2    = (const float*)d_in[7];
    const float* W0    = (const float*)d_in[8];
    const float* Wa    = (const float*)d_in[9];
    const float* W1    = (const float*)d_in[10];

    float* out = (float*)d_out;
    const long long ROWS = 8LL * 2048;          // 16384
    const long long HN   = ROWS * 128;          // 2097152

    // workspace layout
    float* xnew = (float*)d_ws;                           // 2097152 f32
    float* s1   = xnew + HN;                              // 16384
    float* s2   = s1 + ROWS;                              // 16384
    float* Cc   = s2 + ROWS;                              // 16384
    unsigned short* hT  = (unsigned short*)(Cc + ROWS);   // 2097152 bf16
    unsigned short* Web = hT + HN;                        // 8192
    unsigned short* W0b = Web + 128 * 64;                 // 16384
    unsigned short* W1b = W0b + 128 * 128;                // 16384

    float* atten = out + HN;        // 8*2048*2048 f32 output region
    float* attn  = out;             // attentioned parked in h_next region

    kW<<<64, 256, 0, stream>>>(W_enc, W0, W1, Web, W0b, W1b);
    kA<<<512, 256, 0, stream>>>(x, enc, Web, b_enc, g1, b1, W0b, Wa,
                                xnew, hT, s1, s2);
    kC<<<4096, 256, 0, stream>>>(s1, s2, Cc);
    kD<<<512, 256, 0, stream>>>(s1, s2, Cc, hT, atten, attn);
    kE<<<512, 256, 0, stream>>>(xnew, g2, b2, W1b, out);
}

// Round 4
// 238.309 us; speedup vs baseline: 2.3502x; 1.1636x over previous
//
#include <hip/hip_runtime.h>
#include <hip/hip_bf16.h>
#include <cstddef>

#define EPS 1e-5f
#define NSLOPE 0.01f

typedef __attribute__((ext_vector_type(8))) short s16x8;   // 8 bf16 (4 VGPRs)
typedef __attribute__((ext_vector_type(4))) float f32x4;

union BF8 { unsigned short u[8]; s16x8 v; };

static __device__ inline unsigned short f2bf(float f) {
    unsigned int u = __float_as_uint(f);
    u += 0x7fffu + ((u >> 16) & 1u);   // round-to-nearest-even
    return (unsigned short)(u >> 16);
}

// ---------------- Kernel W: cast weights to bf16 row-major -----------------
__global__ __launch_bounds__(256) void kW(
    const float* __restrict__ W_enc, const float* __restrict__ W0,
    const float* __restrict__ W1,
    unsigned short* __restrict__ Web, unsigned short* __restrict__ W0b,
    unsigned short* __restrict__ W1b)
{
    int idx = blockIdx.x * 256 + threadIdx.x;
    if (idx < 128 * 64) Web[idx] = f2bf(W_enc[idx]);
    if (idx < 128 * 128) { W0b[idx] = f2bf(W0[idx]); W1b[idx] = f2bf(W1[idx]); }
}

// ---------------- Kernel A -------------------------------------------------
// 32 rows/block. 4 waves: w&1 -> 16-row strip, w>>1 -> 64-col half.
// GEMM1 (enc@WencT,K=64) -> +x+b_enc -> LN1 -> GEMM2 (xn@W0T,K=128)
// -> s1,s2 row-dots; h written transposed into hP[b][jtile][128][32] tiles.
__global__ __launch_bounds__(256, 4) void kA(
    const float* __restrict__ x, const float* __restrict__ enc,
    const unsigned short* __restrict__ Web, const float* __restrict__ b_enc,
    const float* __restrict__ g1, const float* __restrict__ b1,
    const unsigned short* __restrict__ W0b, const float* __restrict__ Wa,
    float* __restrict__ xnew, unsigned short* __restrict__ hP,
    float* __restrict__ s1, float* __restrict__ s2)
{
    __shared__ float ys[32][132];             // y rows (f32) for LN
    __shared__ unsigned short xnb[32][136];   // LN output (bf16) A-frags
    __shared__ unsigned short hts[128][40];   // h transposed (bf16)
    __shared__ float ps1[2][32], ps2[2][32];  // s1/s2 partials per col-half

    int t = threadIdx.x;
    int w = t >> 6, lane = t & 63;
    int ml = lane & 15, quad = lane >> 4;
    int mrow = (w & 1) * 16;
    int chalf = (w >> 1) * 64;
    long long R0 = (long long)blockIdx.x * 32;
    int b = (int)(R0 >> 11);
    int jt = (int)((R0 & 2047) >> 5);        // j-tile index within batch

    // ---- GEMM1: acc1 = enc @ WencT (K=64) ----
    f32x4 acc1[4] = {};
    const float* encrow = enc + (R0 + mrow + ml) * 64 + quad * 8;
#pragma unroll
    for (int kb = 0; kb < 2; ++kb) {
        float4 e0 = *(const float4*)(encrow + kb * 32);
        float4 e1 = *(const float4*)(encrow + kb * 32 + 4);
        BF8 af;
        af.u[0] = f2bf(e0.x); af.u[1] = f2bf(e0.y);
        af.u[2] = f2bf(e0.z); af.u[3] = f2bf(e0.w);
        af.u[4] = f2bf(e1.x); af.u[5] = f2bf(e1.y);
        af.u[6] = f2bf(e1.z); af.u[7] = f2bf(e1.w);
#pragma unroll
        for (int ct = 0; ct < 4; ++ct) {
            int n = chalf + ct * 16 + ml;
            s16x8 bf = *(const s16x8*)(Web + n * 64 + kb * 32 + quad * 8);
            acc1[ct] = __builtin_amdgcn_mfma_f32_16x16x32_bf16(af.v, bf, acc1[ct], 0, 0, 0);
        }
    }
#pragma unroll
    for (int ct = 0; ct < 4; ++ct) {
        int col = chalf + ct * 16 + ml;
        float be = b_enc[col];
#pragma unroll
        for (int rg = 0; rg < 4; ++rg) {
            int rl = mrow + quad * 4 + rg;
            long long row = R0 + rl;
            float y = acc1[ct][rg] + x[row * 128 + col] + be;
            xnew[row * 128 + col] = y;
            ys[rl][col] = y;
        }
    }
    __syncthreads();

    // ---- LN1: 8 threads per row ----
    {
        int rl = t >> 3, sub = t & 7;
        float v[16];
        float s = 0.f, q = 0.f;
#pragma unroll
        for (int i = 0; i < 16; ++i) {
            v[i] = ys[rl][sub * 16 + i];
            s += v[i]; q += v[i] * v[i];
        }
#pragma unroll
        for (int m = 1; m < 8; m <<= 1) { s += __shfl_xor(s, m); q += __shfl_xor(q, m); }
        float mean = s * (1.f / 128.f);
        float var = q * (1.f / 128.f) - mean * mean;
        float rstd = rsqrtf(var + EPS);
#pragma unroll
        for (int i = 0; i < 16; ++i) {
            int col = sub * 16 + i;
            float xn = (v[i] - mean) * rstd * g1[col] + b1[col];
            xnb[rl][col] = f2bf(xn);
        }
    }
    __syncthreads();

    // ---- GEMM2: h = xn @ W0T (K=128) ----
    f32x4 acc2[4] = {};
#pragma unroll
    for (int kb = 0; kb < 4; ++kb) {
        s16x8 af = *(const s16x8*)(&xnb[mrow + ml][kb * 32 + quad * 8]);
#pragma unroll
        for (int ct = 0; ct < 4; ++ct) {
            int n = chalf + ct * 16 + ml;
            s16x8 bf = *(const s16x8*)(W0b + n * 128 + kb * 32 + quad * 8);
            acc2[ct] = __builtin_amdgcn_mfma_f32_16x16x32_bf16(af, bf, acc2[ct], 0, 0, 0);
        }
    }

    // ---- epilogue: hts stash + s1/s2 partial dots ----
#pragma unroll
    for (int ct = 0; ct < 4; ++ct) {
        int col = chalf + ct * 16 + ml;
#pragma unroll
        for (int rg = 0; rg < 4; ++rg)
            hts[col][mrow + quad * 4 + rg] = f2bf(acc2[ct][rg]);
    }
#pragma unroll
    for (int rg = 0; rg < 4; ++rg) {
        float p1 = 0.f, p2 = 0.f;
#pragma unroll
        for (int ct = 0; ct < 4; ++ct) {
            int col = chalf + ct * 16 + ml;
            p1 += acc2[ct][rg] * Wa[col];
            p2 += acc2[ct][rg] * Wa[128 + col];
        }
#pragma unroll
        for (int m = 1; m < 16; m <<= 1) { p1 += __shfl_xor(p1, m); p2 += __shfl_xor(p2, m); }
        if (ml == 0) {
            int rl = mrow + quad * 4 + rg;
            ps1[w >> 1][rl] = p1;
            ps2[w >> 1][rl] = p2;
        }
    }
    __syncthreads();
    if (t < 32) {
        s1[R0 + t] = ps1[0][t] + ps1[1][t];
        s2[R0 + t] = ps2[0][t] + ps2[1][t];
    }
    // hP store: tile [128 cc][32 j], fully coalesced
    {
        int c = t >> 1, half = t & 1;
        unsigned short* dst = hP + (((long long)b * 64 + jt) * 128 + c) * 32 + half * 16;
        const unsigned short* srcp = &hts[c][half * 16];
        *(s16x8*)(dst) = *(const s16x8*)(srcp);
        *(s16x8*)(dst + 8) = *(const s16x8*)(srcp + 8);
    }
}

// ---------------- Kernel C: per-row softmax constant C_i = m_i + log(l_i) ---
__global__ __launch_bounds__(256) void kC(const float* __restrict__ s1,
                                          const float* __restrict__ s2,
                                          float* __restrict__ Cc)
{
    int t = threadIdx.x;
    int w = t >> 6, lane = t & 63;
    long long row = (long long)blockIdx.x * 4 + w;
    int b = (int)(row >> 11);
    const float* s2b = s2 + (long long)b * 2048;
    float s1i = s1[row];

    float mx = -1e30f;
    for (int j = lane; j < 2048; j += 64) mx = fmaxf(mx, s2b[j]);
    for (int m = 32; m; m >>= 1) mx = fmaxf(mx, __shfl_xor(mx, m));
    float z0 = s1i + mx;
    float mi = fmaxf(z0, NSLOPE * z0);   // lrelu is monotone -> row max

    float l = 0.f;
    for (int j = lane; j < 2048; j += 64) {
        float z = s1i + s2b[j];
        float zl = fmaxf(z, NSLOPE * z);
        l += __expf(zl - mi);
    }
    for (int m = 32; m; m >>= 1) l += __shfl_xor(l, m);
    if (lane == 0) Cc[row] = mi + __logf(l);
}

// ---------------- Kernel D: write atten (f32) + attentioned = atten @ h -----
// block = 16 rows, 4 waves: w&1 -> j-half (1024 each), w>>1 -> 64-col half.
// grid = 8 b * 128 i-tiles = 1024 blocks -> 4 blocks/CU, 16 waves/CU.
__global__ __launch_bounds__(256, 4) void kD(
    const float* __restrict__ s1, const float* __restrict__ s2,
    const float* __restrict__ Cc, const unsigned short* __restrict__ hP,
    float* __restrict__ atten, float* __restrict__ attn)
{
    __shared__ float Pt[2][16][36];    // p transpose buffer per j-half wave
    __shared__ float R[2][16][68];     // j-partial reduce per c-half

    int t = threadIdx.x;
    int w = t >> 6, lane = t & 63;
    int jh = w & 1, ch = w >> 1;
    int chalf = ch * 64;
    int b = blockIdx.x >> 7;           // 128 i-tiles (16 rows each) per batch
    int it = blockIdx.x & 127;
    int i0 = it * 16;
    int ml = lane & 15, quad = lane >> 4;

    long long gi = (long long)b * 2048 + i0 + ml;
    float s1i = s1[gi];
    float Ci = Cc[gi];
    const float* s2b = s2 + (long long)b * 2048;
    const unsigned short* hPb = hP + (long long)b * 64 * 128 * 32;

    // store-role addressing (coalesced): row = lane>>3, col-chunk = lane&7
    int sr = lane >> 3, sc = lane & 7;
    float* abase = atten + ((long long)b * 2048 + i0) * 2048;

    f32x4 acc[4] = {};
    for (int jj = 0; jj < 1024; jj += 32) {
        int j0 = jh * 1024 + jj;
        int jb = j0 + quad * 8;
        float4 sa = *(const float4*)(s2b + jb);
        float4 sb = *(const float4*)(s2b + jb + 4);
        float zs[8] = {sa.x, sa.y, sa.z, sa.w, sb.x, sb.y, sb.z, sb.w};
        float p[8];
        BF8 af;
#pragma unroll
        for (int k = 0; k < 8; ++k) {
            float z = s1i + zs[k];
            float zl = fmaxf(z, NSLOPE * z);
            p[k] = __expf(zl - Ci);          // = exp(lrelu-m)/l
            af.u[k] = f2bf(p[k]);
        }
        if (ch == 0) {
            // wave-local LDS transpose -> coalesced 128B-per-row stores
            *(f32x4*)&Pt[jh][ml][quad * 8]     = *(const f32x4*)&p[0];
            *(f32x4*)&Pt[jh][ml][quad * 8 + 4] = *(const f32x4*)&p[4];
            f32x4 r0 = *(const f32x4*)&Pt[jh][sr][sc * 4];
            f32x4 r1 = *(const f32x4*)&Pt[jh][8 + sr][sc * 4];
            *(f32x4*)(abase + (long long)sr * 2048 + j0 + sc * 4) = r0;
            *(f32x4*)(abase + (long long)(8 + sr) * 2048 + j0 + sc * 4) = r1;
        }
        const unsigned short* tb = hPb + (long long)(j0 >> 5) * 128 * 32;
#pragma unroll
        for (int ct = 0; ct < 4; ++ct) {
            s16x8 bfrag = *(const s16x8*)(tb + (chalf + ct * 16 + ml) * 32 + quad * 8);
            acc[ct] = __builtin_amdgcn_mfma_f32_16x16x32_bf16(af.v, bfrag, acc[ct], 0, 0, 0);
        }
    }

    // combine j-halves: jh==1 writes partials, jh==0 adds and stores attn
    if (jh == 1) {
#pragma unroll
        for (int ct = 0; ct < 4; ++ct)
#pragma unroll
            for (int rg = 0; rg < 4; ++rg)
                R[ch][quad * 4 + rg][ct * 16 + ml] = acc[ct][rg];
    }
    __syncthreads();
    if (jh == 0) {
#pragma unroll
        for (int ct = 0; ct < 4; ++ct) {
#pragma unroll
            for (int rg = 0; rg < 4; ++rg) {
                int ii = quad * 4 + rg;
                float v = acc[ct][rg] + R[ch][ii][ct * 16 + ml];
                attn[((long long)b * 2048 + i0 + ii) * 128 + chalf + ct * 16 + ml] = v;
            }
        }
    }
}

// ---------------- Kernel E: residual + LN2 + W1^T + elu (in-place) ---------
__global__ __launch_bounds__(256, 4) void kE(
    const float* __restrict__ xnew, const float* __restrict__ g2,
    const float* __restrict__ b2, const unsigned short* __restrict__ W1b,
    float* __restrict__ io)
{
    __shared__ unsigned short xnb[32][136];
    int t = threadIdx.x;
    long long R0 = (long long)blockIdx.x * 32;

    {
        int rl = t >> 3, sub = t & 7;
        long long row = R0 + rl;
        const float* pio = io + row * 128 + sub * 16;
        const float* pxn = xnew + row * 128 + sub * 16;
        float v[16];
        float s = 0.f, q = 0.f;
#pragma unroll
        for (int i = 0; i < 16; i += 4) {
            float4 a = *(const float4*)(pio + i);
            float4 c = *(const float4*)(pxn + i);
            v[i]     = a.x + c.x; v[i + 1] = a.y + c.y;
            v[i + 2] = a.z + c.z; v[i + 3] = a.w + c.w;
        }
#pragma unroll
        for (int i = 0; i < 16; ++i) { s += v[i]; q += v[i] * v[i]; }
#pragma unroll
        for (int m = 1; m < 8; m <<= 1) { s += __shfl_xor(s, m); q += __shfl_xor(q, m); }
        float mean = s * (1.f / 128.f);
        float var = q * (1.f / 128.f) - mean * mean;
        float rstd = rsqrtf(var + EPS);
#pragma unroll
        for (int i = 0; i < 16; ++i) {
            int col = sub * 16 + i;
            float xn = (v[i] - mean) * rstd * g2[col] + b2[col];
            xnb[rl][col] = f2bf(xn);
        }
    }
    __syncthreads();

    int w = t >> 6, lane = t & 63;
    int ml = lane & 15, quad = lane >> 4;
    int mrow = (w & 1) * 16;
    int chalf = (w >> 1) * 64;

    f32x4 acc[4] = {};
#pragma unroll
    for (int kb = 0; kb < 4; ++kb) {
        s16x8 af = *(const s16x8*)(&xnb[mrow + ml][kb * 32 + quad * 8]);
#pragma unroll
        for (int ct = 0; ct < 4; ++ct) {
            int n = chalf + ct * 16 + ml;
            s16x8 bf = *(const s16x8*)(W1b + n * 128 + kb * 32 + quad * 8);
            acc[ct] = __builtin_amdgcn_mfma_f32_16x16x32_bf16(af, bf, acc[ct], 0, 0, 0);
        }
    }
#pragma unroll
    for (int ct = 0; ct < 4; ++ct) {
        int col = chalf + ct * 16 + ml;
#pragma unroll
        for (int rg = 0; rg < 4; ++rg) {
            int rl = mrow + quad * 4 + rg;
            float h = acc[ct][rg];
            float o = h > 0.f ? h : (__expf(h) - 1.f);
            io[(R0 + rl) * 128 + col] = o;
        }
    }
}

extern "C" void kernel_launch(void* const* d_in, const int* in_sizes, int n_in,
                              void* d_out, int out_size, void* d_ws, size_t ws_size,
                              hipStream_t stream)
{
    const float* x     = (const float*)d_in[0];
    const float* enc   = (const float*)d_in[1];
    const float* W_enc = (const float*)d_in[2];
    const float* b_enc = (const float*)d_in[3];
    const float* g1    = (const float*)d_in[4];
    const float* b1    = (const float*)d_in[5];
    const float* g2    = (const float*)d_in[6];
    const float* b2    = (const float*)d_in[7];
    const float* W0    = (const float*)d_in[8];
    const float* Wa    = (const float*)d_in[9];
    const float* W1    = (const float*)d_in[10];

    float* out = (float*)d_out;
    const long long ROWS = 8LL * 2048;          // 16384
    const long long HN   = ROWS * 128;          // 2097152

    // workspace layout
    float* xnew = (float*)d_ws;                           // 2097152 f32
    float* s1   = xnew + HN;                              // 16384
    float* s2   = s1 + ROWS;                              // 16384
    float* Cc   = s2 + ROWS;                              // 16384
    unsigned short* hP  = (unsigned short*)(Cc + ROWS);   // 2097152 bf16
    unsigned short* Web = hP + HN;                        // 8192
    unsigned short* W0b = Web + 128 * 64;                 // 16384
    unsigned short* W1b = W0b + 128 * 128;                // 16384

    float* atten = out + HN;        // 8*2048*2048 f32 output region
    float* attn  = out;             // attentioned parked in h_next region

    kW<<<64, 256, 0, stream>>>(W_enc, W0, W1, Web, W0b, W1b);
    kA<<<512, 256, 0, stream>>>(x, enc, Web, b_enc, g1, b1, W0b, Wa,
                                xnew, hP, s1, s2);
    kC<<<4096, 256, 0, stream>>>(s1, s2, Cc);
    kD<<<1024, 256, 0, stream>>>(s1, s2, Cc, hP, atten, attn);
    kE<<<512, 256, 0, stream>>>(xnew, g2, b2, W1b, out);
}

// Round 5
// 233.351 us; speedup vs baseline: 2.4002x; 1.0212x over previous
//
#include <hip/hip_runtime.h>
#include <hip/hip_bf16.h>
#include <cstddef>

#define EPS 1e-5f
#define NSLOPE 0.01f

typedef __attribute__((ext_vector_type(8))) short s16x8;   // 8 bf16 (4 VGPRs)
typedef __attribute__((ext_vector_type(4))) float f32x4;

union BF8 { unsigned short u[8]; s16x8 v; };

static __device__ inline unsigned short f2bf(float f) {
    unsigned int u = __float_as_uint(f);
    u += 0x7fffu + ((u >> 16) & 1u);   // round-to-nearest-even
    return (unsigned short)(u >> 16);
}

static __device__ inline void nt_store4(float* p, f32x4 v) {
    __builtin_nontemporal_store(v, (f32x4*)p);
}

// ---------------- Kernel W: cast weights to bf16 row-major -----------------
__global__ __launch_bounds__(256) void kW(
    const float* __restrict__ W_enc, const float* __restrict__ W0,
    const float* __restrict__ W1,
    unsigned short* __restrict__ Web, unsigned short* __restrict__ W0b,
    unsigned short* __restrict__ W1b)
{
    int idx = blockIdx.x * 256 + threadIdx.x;
    if (idx < 128 * 64) Web[idx] = f2bf(W_enc[idx]);
    if (idx < 128 * 128) { W0b[idx] = f2bf(W0[idx]); W1b[idx] = f2bf(W1[idx]); }
}

// ---------------- Kernel A -------------------------------------------------
// 32 rows/block. 4 waves: w&1 -> 16-row strip, w>>1 -> 64-col half.
// GEMM1 (enc@WencT,K=64) -> +x+b_enc -> LN1 -> GEMM2 (xn@W0T,K=128)
// -> s1,s2 row-dots; h written transposed into hP[b][jtile][128][32] tiles.
__global__ __launch_bounds__(256, 4) void kA(
    const float* __restrict__ x, const float* __restrict__ enc,
    const unsigned short* __restrict__ Web, const float* __restrict__ b_enc,
    const float* __restrict__ g1, const float* __restrict__ b1,
    const unsigned short* __restrict__ W0b, const float* __restrict__ Wa,
    float* __restrict__ xnew, unsigned short* __restrict__ hP,
    float* __restrict__ s1, float* __restrict__ s2)
{
    __shared__ float ys[32][132];             // y rows (f32) for LN
    __shared__ unsigned short xnb[32][136];   // LN output (bf16) A-frags
    __shared__ unsigned short hts[128][40];   // h transposed (bf16)
    __shared__ float ps1[2][32], ps2[2][32];  // s1/s2 partials per col-half

    int t = threadIdx.x;
    int w = t >> 6, lane = t & 63;
    int ml = lane & 15, quad = lane >> 4;
    int mrow = (w & 1) * 16;
    int chalf = (w >> 1) * 64;
    long long R0 = (long long)blockIdx.x * 32;
    int b = (int)(R0 >> 11);
    int jt = (int)((R0 & 2047) >> 5);        // j-tile index within batch

    // ---- GEMM1: acc1 = enc @ WencT (K=64) ----
    f32x4 acc1[4] = {};
    const float* encrow = enc + (R0 + mrow + ml) * 64 + quad * 8;
#pragma unroll
    for (int kb = 0; kb < 2; ++kb) {
        float4 e0 = *(const float4*)(encrow + kb * 32);
        float4 e1 = *(const float4*)(encrow + kb * 32 + 4);
        BF8 af;
        af.u[0] = f2bf(e0.x); af.u[1] = f2bf(e0.y);
        af.u[2] = f2bf(e0.z); af.u[3] = f2bf(e0.w);
        af.u[4] = f2bf(e1.x); af.u[5] = f2bf(e1.y);
        af.u[6] = f2bf(e1.z); af.u[7] = f2bf(e1.w);
#pragma unroll
        for (int ct = 0; ct < 4; ++ct) {
            int n = chalf + ct * 16 + ml;
            s16x8 bf = *(const s16x8*)(Web + n * 64 + kb * 32 + quad * 8);
            acc1[ct] = __builtin_amdgcn_mfma_f32_16x16x32_bf16(af.v, bf, acc1[ct], 0, 0, 0);
        }
    }
#pragma unroll
    for (int ct = 0; ct < 4; ++ct) {
        int col = chalf + ct * 16 + ml;
        float be = b_enc[col];
#pragma unroll
        for (int rg = 0; rg < 4; ++rg) {
            int rl = mrow + quad * 4 + rg;
            long long row = R0 + rl;
            float y = acc1[ct][rg] + x[row * 128 + col] + be;
            xnew[row * 128 + col] = y;
            ys[rl][col] = y;
        }
    }
    __syncthreads();

    // ---- LN1: 8 threads per row ----
    {
        int rl = t >> 3, sub = t & 7;
        float v[16];
        float s = 0.f, q = 0.f;
#pragma unroll
        for (int i = 0; i < 16; ++i) {
            v[i] = ys[rl][sub * 16 + i];
            s += v[i]; q += v[i] * v[i];
        }
#pragma unroll
        for (int m = 1; m < 8; m <<= 1) { s += __shfl_xor(s, m); q += __shfl_xor(q, m); }
        float mean = s * (1.f / 128.f);
        float var = q * (1.f / 128.f) - mean * mean;
        float rstd = rsqrtf(var + EPS);
#pragma unroll
        for (int i = 0; i < 16; ++i) {
            int col = sub * 16 + i;
            float xn = (v[i] - mean) * rstd * g1[col] + b1[col];
            xnb[rl][col] = f2bf(xn);
        }
    }
    __syncthreads();

    // ---- GEMM2: h = xn @ W0T (K=128) ----
    f32x4 acc2[4] = {};
#pragma unroll
    for (int kb = 0; kb < 4; ++kb) {
        s16x8 af = *(const s16x8*)(&xnb[mrow + ml][kb * 32 + quad * 8]);
#pragma unroll
        for (int ct = 0; ct < 4; ++ct) {
            int n = chalf + ct * 16 + ml;
            s16x8 bf = *(const s16x8*)(W0b + n * 128 + kb * 32 + quad * 8);
            acc2[ct] = __builtin_amdgcn_mfma_f32_16x16x32_bf16(af, bf, acc2[ct], 0, 0, 0);
        }
    }

    // ---- epilogue: hts stash + s1/s2 partial dots ----
#pragma unroll
    for (int ct = 0; ct < 4; ++ct) {
        int col = chalf + ct * 16 + ml;
#pragma unroll
        for (int rg = 0; rg < 4; ++rg)
            hts[col][mrow + quad * 4 + rg] = f2bf(acc2[ct][rg]);
    }
#pragma unroll
    for (int rg = 0; rg < 4; ++rg) {
        float p1 = 0.f, p2 = 0.f;
#pragma unroll
        for (int ct = 0; ct < 4; ++ct) {
            int col = chalf + ct * 16 + ml;
            p1 += acc2[ct][rg] * Wa[col];
            p2 += acc2[ct][rg] * Wa[128 + col];
        }
#pragma unroll
        for (int m = 1; m < 16; m <<= 1) { p1 += __shfl_xor(p1, m); p2 += __shfl_xor(p2, m); }
        if (ml == 0) {
            int rl = mrow + quad * 4 + rg;
            ps1[w >> 1][rl] = p1;
            ps2[w >> 1][rl] = p2;
        }
    }
    __syncthreads();
    if (t < 32) {
        s1[R0 + t] = ps1[0][t] + ps1[1][t];
        s2[R0 + t] = ps2[0][t] + ps2[1][t];
    }
    // hP store: tile [128 cc][32 j], fully coalesced
    {
        int c = t >> 1, half = t & 1;
        unsigned short* dst = hP + (((long long)b * 64 + jt) * 128 + c) * 32 + half * 16;
        const unsigned short* srcp = &hts[c][half * 16];
        *(s16x8*)(dst) = *(const s16x8*)(srcp);
        *(s16x8*)(dst + 8) = *(const s16x8*)(srcp + 8);
    }
}

// ---------------- Kernel D: softmax const + atten write + atten @ h --------
// block = 16 rows, 4 waves; wave w owns j-range [w*512,(w+1)*512) x all 128
// cols. Every exp computed exactly once; all 4 waves store atten (NT).
// Per-block softmax constants (old kC) computed inline.
__global__ __launch_bounds__(256, 4) void kD(
    const float* __restrict__ s1, const float* __restrict__ s2,
    const unsigned short* __restrict__ hP,
    float* __restrict__ atten, float* __restrict__ attn)
{
    __shared__ float Pt[4][16][36];     // per-wave p-transpose buffer
    __shared__ float Rbuf[3][16][132];  // j-partial reduce
    __shared__ float s1sh[16], Csh[16];

    int t = threadIdx.x;
    int w = t >> 6, lane = t & 63;
    int b = blockIdx.x >> 7;            // 128 i-tiles (16 rows) per batch
    int it = blockIdx.x & 127;
    int i0 = it * 16;
    int ml = lane & 15, quad = lane >> 4;

    const float* s2b = s2 + (long long)b * 2048;

    // ---- softmax constants for rows i0..i0+15 (wave w: rows w*4..w*4+3) ----
    float mxs = -1e30f;
    for (int j = lane; j < 2048; j += 64) mxs = fmaxf(mxs, s2b[j]);
#pragma unroll
    for (int m = 32; m; m >>= 1) mxs = fmaxf(mxs, __shfl_xor(mxs, m));
#pragma unroll
    for (int r = 0; r < 4; ++r) {
        int rl = w * 4 + r;
        float s1i = s1[(long long)b * 2048 + i0 + rl];
        float z0 = s1i + mxs;
        float mi = fmaxf(z0, NSLOPE * z0);   // lrelu monotone -> row max
        float l = 0.f;
        for (int j = lane; j < 2048; j += 64) {
            float z = s1i + s2b[j];
            float zl = fmaxf(z, NSLOPE * z);
            l += __expf(zl - mi);
        }
#pragma unroll
        for (int m = 32; m; m >>= 1) l += __shfl_xor(l, m);
        if (lane == 0) { s1sh[rl] = s1i; Csh[rl] = mi + __logf(l); }
    }
    __syncthreads();

    float s1i = s1sh[ml];
    float Ci  = Csh[ml];
    const unsigned short* hPb = hP + (long long)b * 64 * 128 * 32;
    int sr = lane >> 3, sc = lane & 7;
    float* abase = atten + ((long long)b * 2048 + i0) * 2048;

    f32x4 acc[8] = {};
    for (int jj = 0; jj < 512; jj += 32) {
        int j0 = w * 512 + jj;
        int jb = j0 + quad * 8;
        float4 sa = *(const float4*)(s2b + jb);
        float4 sb = *(const float4*)(s2b + jb + 4);
        float zs[8] = {sa.x, sa.y, sa.z, sa.w, sb.x, sb.y, sb.z, sb.w};
        float p[8];
        BF8 af;
#pragma unroll
        for (int k = 0; k < 8; ++k) {
            float z = s1i + zs[k];
            float zl = fmaxf(z, NSLOPE * z);
            p[k] = __expf(zl - Ci);          // = exp(lrelu-m)/l
            af.u[k] = f2bf(p[k]);
        }
        // wave-local LDS transpose -> coalesced 128B-per-row NT stores
        *(f32x4*)&Pt[w][ml][quad * 8]     = *(const f32x4*)&p[0];
        *(f32x4*)&Pt[w][ml][quad * 8 + 4] = *(const f32x4*)&p[4];
        f32x4 r0 = *(const f32x4*)&Pt[w][sr][sc * 4];
        f32x4 r1 = *(const f32x4*)&Pt[w][8 + sr][sc * 4];
        nt_store4(abase + (long long)sr * 2048 + j0 + sc * 4, r0);
        nt_store4(abase + (long long)(8 + sr) * 2048 + j0 + sc * 4, r1);

        const unsigned short* tb = hPb + (long long)(j0 >> 5) * 128 * 32;
#pragma unroll
        for (int ct = 0; ct < 8; ++ct) {
            s16x8 bfrag = *(const s16x8*)(tb + (ct * 16 + ml) * 32 + quad * 8);
            acc[ct] = __builtin_amdgcn_mfma_f32_16x16x32_bf16(af.v, bfrag, acc[ct], 0, 0, 0);
        }
    }

    // ---- combine j-quarters ----
    if (w > 0) {
#pragma unroll
        for (int ct = 0; ct < 8; ++ct)
#pragma unroll
            for (int rg = 0; rg < 4; ++rg)
                Rbuf[w - 1][quad * 4 + rg][ct * 16 + ml] = acc[ct][rg];
    }
    __syncthreads();
    if (w == 0) {
#pragma unroll
        for (int ct = 0; ct < 8; ++ct) {
#pragma unroll
            for (int rg = 0; rg < 4; ++rg) {
                int ii = quad * 4 + rg;
                int cc = ct * 16 + ml;
                float v = acc[ct][rg] + Rbuf[0][ii][cc] + Rbuf[1][ii][cc]
                        + Rbuf[2][ii][cc];
                attn[((long long)b * 2048 + i0 + ii) * 128 + cc] = v;
            }
        }
    }
}

// ---------------- Kernel E: residual + LN2 + W1^T + elu (in-place) ---------
__global__ __launch_bounds__(256, 4) void kE(
    const float* __restrict__ xnew, const float* __restrict__ g2,
    const float* __restrict__ b2, const unsigned short* __restrict__ W1b,
    float* __restrict__ io)
{
    __shared__ unsigned short xnb[32][136];
    int t = threadIdx.x;
    long long R0 = (long long)blockIdx.x * 32;

    {
        int rl = t >> 3, sub = t & 7;
        long long row = R0 + rl;
        const float* pio = io + row * 128 + sub * 16;
        const float* pxn = xnew + row * 128 + sub * 16;
        float v[16];
        float s = 0.f, q = 0.f;
#pragma unroll
        for (int i = 0; i < 16; i += 4) {
            float4 a = *(const float4*)(pio + i);
            float4 c = *(const float4*)(pxn + i);
            v[i]     = a.x + c.x; v[i + 1] = a.y + c.y;
            v[i + 2] = a.z + c.z; v[i + 3] = a.w + c.w;
        }
#pragma unroll
        for (int i = 0; i < 16; ++i) { s += v[i]; q += v[i] * v[i]; }
#pragma unroll
        for (int m = 1; m < 8; m <<= 1) { s += __shfl_xor(s, m); q += __shfl_xor(q, m); }
        float mean = s * (1.f / 128.f);
        float var = q * (1.f / 128.f) - mean * mean;
        float rstd = rsqrtf(var + EPS);
#pragma unroll
        for (int i = 0; i < 16; ++i) {
            int col = sub * 16 + i;
            float xn = (v[i] - mean) * rstd * g2[col] + b2[col];
            xnb[rl][col] = f2bf(xn);
        }
    }
    __syncthreads();

    int w = t >> 6, lane = t & 63;
    int ml = lane & 15, quad = lane >> 4;
    int mrow = (w & 1) * 16;
    int chalf = (w >> 1) * 64;

    f32x4 acc[4] = {};
#pragma unroll
    for (int kb = 0; kb < 4; ++kb) {
        s16x8 af = *(const s16x8*)(&xnb[mrow + ml][kb * 32 + quad * 8]);
#pragma unroll
        for (int ct = 0; ct < 4; ++ct) {
            int n = chalf + ct * 16 + ml;
            s16x8 bf = *(const s16x8*)(W1b + n * 128 + kb * 32 + quad * 8);
            acc[ct] = __builtin_amdgcn_mfma_f32_16x16x32_bf16(af, bf, acc[ct], 0, 0, 0);
        }
    }
#pragma unroll
    for (int ct = 0; ct < 4; ++ct) {
        int col = chalf + ct * 16 + ml;
#pragma unroll
        for (int rg = 0; rg < 4; ++rg) {
            int rl = mrow + quad * 4 + rg;
            float h = acc[ct][rg];
            float o = h > 0.f ? h : (__expf(h) - 1.f);
            io[(R0 + rl) * 128 + col] = o;
        }
    }
}

extern "C" void kernel_launch(void* const* d_in, const int* in_sizes, int n_in,
                              void* d_out, int out_size, void* d_ws, size_t ws_size,
                              hipStream_t stream)
{
    const float* x     = (const float*)d_in[0];
    const float* enc   = (const float*)d_in[1];
    const float* W_enc = (const float*)d_in[2];
    const float* b_enc = (const float*)d_in[3];
    const float* g1    = (const float*)d_in[4];
    const float* b1    = (const float*)d_in[5];
    const float* g2    = (const float*)d_in[6];
    const float* b2    = (const float*)d_in[7];
    const float* W0    = (const float*)d_in[8];
    const float* Wa    = (const float*)d_in[9];
    const float* W1    = (const float*)d_in[10];

    float* out = (float*)d_out;
    const long long ROWS = 8LL * 2048;          // 16384
    const long long HN   = ROWS * 128;          // 2097152

    // workspace layout
    float* xnew = (float*)d_ws;                           // 2097152 f32
    float* s1   = xnew + HN;                              // 16384
    float* s2   = s1 + ROWS;                              // 16384
    unsigned short* hP  = (unsigned short*)(s2 + ROWS);   // 2097152 bf16
    unsigned short* Web = hP + HN;                        // 8192
    unsigned short* W0b = Web + 128 * 64;                 // 16384
    unsigned short* W1b = W0b + 128 * 128;                // 16384

    float* atten = out + HN;        // 8*2048*2048 f32 output region
    float* attn  = out;             // attentioned parked in h_next region

    kW<<<64, 256, 0, stream>>>(W_enc, W0, W1, Web, W0b, W1b);
    kA<<<512, 256, 0, stream>>>(x, enc, Web, b_enc, g1, b1, W0b, Wa,
                                xnew, hP, s1, s2);
    kD<<<1024, 256, 0, stream>>>(s1, s2, hP, atten, attn);
    kE<<<512, 256, 0, stream>>>(xnew, g2, b2, W1b, out);
}